// Round 1
// baseline (3719.925 us; speedup 1.0000x reference)
//
#include <hip/hip_runtime.h>

// Problem constants
constexpr int   kNIN   = 12;
constexpr int   kNU    = 40;
constexpr int   kNB    = 108;    // B_hat rows = NIN*(N-1)
constexpr int   kNINEQ = 148;
constexpr int   kBATCH = 4096;
constexpr int   kITERS = 20;
constexpr float kSIGMA = 0.1f;
constexpr float kBIG   = 1e9f;
constexpr float kEPS   = 1e-4f;
constexpr int   BPST   = 44;     // padded row stride of permuted B_hat (16B-aligned rows, odd-ish banking)

// ---------------------------------------------------------------------------
// Kernel 1: build Q_hat [40x40], permuted B_hat [108x44], h [148] (tiny, 1 block)
// ---------------------------------------------------------------------------
__global__ void setup_kernel(const float* __restrict__ L, const float* __restrict__ LP,
                             const float* __restrict__ LR, const float* __restrict__ A,
                             const float* __restrict__ Bm, const float* __restrict__ u0,
                             const float* __restrict__ s0,
                             float* __restrict__ Qg, float* __restrict__ Bpg,
                             float* __restrict__ hg)
{
    __shared__ float sQx[144], sP[144], sR[16], sM[9][48];
    __shared__ float sBh[108 * 40], sQB[108 * 40];
    const int tid = threadIdx.x;

    // Qx = tril(L) tril(L)^T + eps I ; P likewise from L_P
    for (int idx = tid; idx < 144; idx += 256) {
        int i = idx / 12, j = idx % 12, mn = (i < j) ? i : j;
        float a1 = 0.f, a2 = 0.f;
        for (int k = 0; k <= mn; ++k) {
            a1 = fmaf(L[i * 12 + k],  L[j * 12 + k],  a1);
            a2 = fmaf(LP[i * 12 + k], LP[j * 12 + k], a2);
        }
        if (i == j) { a1 += kEPS; a2 += kEPS; }
        sQx[idx] = a1; sP[idx] = a2;
    }
    if (tid < 16) {
        int i = tid / 4, j = tid % 4, mn = (i < j) ? i : j;
        float a = 0.f;
        for (int k = 0; k <= mn; ++k) a = fmaf(LR[i * 4 + k], LR[j * 4 + k], a);
        if (i == j) a += kEPS;
        sR[tid] = a;
    }
    if (tid < 48) sM[0][tid] = Bm[tid];   // M[0] = B (12x4)
    __syncthreads();
    // M[r] = A @ M[r-1]
    for (int r = 1; r < 9; ++r) {
        if (tid < 48) {
            int i = tid / 4, c = tid % 4;
            float acc = 0.f;
            for (int k = 0; k < 12; ++k) acc = fmaf(A[i * 12 + k], sM[r - 1][k * 4 + c], acc);
            sM[r][tid] = acc;
        }
        __syncthreads();
    }
    // B_hat[j][i]: block r = j/12, col-block c = i/4: A^{r-c} B if c<=r else 0
    for (int idx = tid; idx < 108 * 40; idx += 256) {
        int j = idx / 40, i = idx % 40, r = j / 12, rr = j % 12, c = i / 4, cc = i % 4;
        sBh[idx] = (c <= r) ? sM[r - c][rr * 4 + cc] : 0.f;
    }
    __syncthreads();
    // QB = Q_diag @ B_hat  (block r uses Qx for r<8, P for r=8)
    for (int idx = tid; idx < 108 * 40; idx += 256) {
        int j = idx / 40, i = idx % 40, r = j / 12, rr = j % 12;
        const float* Qb = (r < 8) ? sQx : sP;
        float acc = 0.f;
        for (int kk = 0; kk < 12; ++kk) acc = fmaf(Qb[rr * 12 + kk], sBh[(12 * r + kk) * 40 + i], acc);
        sQB[idx] = acc;
    }
    __syncthreads();
    // Q_hat = B_hat^T QB + R_diag
    for (int idx = tid; idx < 1600; idx += 256) {
        int i = idx / 40, k = idx % 40;
        float acc = 0.f;
        for (int j = 0; j < 108; ++j) acc = fmaf(sBh[j * 40 + i], sQB[j * 40 + k], acc);
        if (i / 4 == k / 4) acc += sR[(i % 4) * 4 + (k % 4)];
        Qg[idx] = acc;
    }
    // permuted/padded B_hat: Bp[j][m], m = li*5+a  <->  col = li + 8a
    for (int idx = tid; idx < 108 * BPST; idx += 256) {
        int j = idx / BPST, m = idx % BPST;
        Bpg[idx] = (m < 40) ? sBh[j * 40 + (m / 5) + 8 * (m % 5)] : 0.f;
    }
    // h = G u0 + s0
    for (int idx = tid; idx < kNINEQ; idx += 256) {
        float acc;
        if (idx < 40) acc = u0[idx];
        else {
            acc = 0.f;
            for (int i = 0; i < 40; ++i) acc = fmaf(sBh[(idx - 40) * 40 + i], u0[i], acc);
        }
        hg[idx] = acc + s0[idx];
    }
}

// ---------------------------------------------------------------------------
// Kernel 2: fused MLP  p = lrelu( lrelu(x W1^T + b1) W2^T + b2 ) ; one wave/row
// ---------------------------------------------------------------------------
__global__ void mlp_kernel(const float* __restrict__ x, const float* __restrict__ W1,
                           const float* __restrict__ b1, const float* __restrict__ W2,
                           const float* __restrict__ b2, float* __restrict__ pg)
{
    const int b = blockIdx.x, t = threadIdx.x;
    float xr[12];
#pragma unroll
    for (int k = 0; k < 12; ++k) xr[k] = x[b * 12 + k];
    float hv[8];
#pragma unroll
    for (int q = 0; q < 8; ++q) {
        const int hh = q * 64 + t;
        float acc = b1[hh];
#pragma unroll
        for (int k = 0; k < 12; ++k) acc = fmaf(xr[k], W1[hh * 12 + k], acc);
        hv[q] = (acc >= 0.f) ? acc : 0.01f * acc;
    }
    for (int o = 0; o < 40; ++o) {
        float part = 0.f;
#pragma unroll
        for (int q = 0; q < 8; ++q) part = fmaf(hv[q], W2[o * 512 + q * 64 + t], part);
#pragma unroll
        for (int m = 32; m >= 1; m >>= 1) part += __shfl_xor(part, m, 64);
        if (t == o) {
            float v = part + b2[o];
            pg[b * 40 + o] = (v >= 0.f) ? v : 0.01f * v;
        }
    }
}

// ---------------------------------------------------------------------------
// Kernel 3: IPM. 1 wave = 1 batch element, 4 waves/block share LDS copy of Bp.
// ---------------------------------------------------------------------------
__device__ __forceinline__ float waveSum(float v) {
#pragma unroll
    for (int m = 32; m >= 1; m >>= 1) v += __shfl_xor(v, m, 64);
    return v;
}
__device__ __forceinline__ float waveMin(float v) {
#pragma unroll
    for (int m = 32; m >= 1; m >>= 1) v = fminf(v, __shfl_xor(v, m, 64));
    return v;
}
// 40-length dot of a (16B-aligned) Bp row with a 16B-aligned vector
__device__ __forceinline__ float rowdot40(const float* row, const float* v) {
    float acc = 0.f;
#pragma unroll
    for (int m = 0; m < 40; m += 4) {
        float4 a = *reinterpret_cast<const float4*>(row + m);
        float4 b = *reinterpret_cast<const float4*>(v + m);
        acc = fmaf(a.x, b.x, acc); acc = fmaf(a.y, b.y, acc);
        acc = fmaf(a.z, b.z, acc); acc = fmaf(a.w, b.w, acc);
    }
    return acc;
}

__global__ __launch_bounds__(256, 3) void ipm_kernel(
    const float* __restrict__ Qg, const float* __restrict__ Bpg,
    const float* __restrict__ hg, const float* __restrict__ pg,
    float* __restrict__ out)
{
    __shared__ __align__(16) float sBp[kNB * BPST];   // 19008 B, shared by 4 waves
    __shared__ __align__(16) float sH[4][40 * 41];    // 26240 B
    __shared__ float sLam[4][148];                    //  2368 B
    __shared__ float sTmp[4][148];                    //  2368 B
    __shared__ float sD[4][148];                      //  2368 B
    __shared__ __align__(16) float sU[4][40];
    __shared__ __align__(16) float sUp[4][40];
    __shared__ __align__(16) float sDup[4][40];       // total 54272 B -> 3 blocks/CU

    const int tid = threadIdx.x;
    const int w = tid >> 6;
    const int t = tid & 63;
    const int e = blockIdx.x * 4 + w;

    for (int i = tid; i < kNB * BPST; i += 256) sBp[i] = Bpg[i];
    __syncthreads();

    const int li = t & 7, lk = t >> 3;
    const int pp = (t & 7) * 5 + (t >> 3);            // pos(t), valid for t<40

    float u_r = 0.f;
    const float p_r = (t < 40) ? pg[e * 40 + t] : 0.f;
    const float h0 = hg[t], h1 = hg[64 + t], h2 = (t < 20) ? hg[128 + t] : 0.f;
    float s0 = 1.f, s1 = 1.f, s2 = 1.f, l0 = 1.f, l1 = 1.f, l2 = 1.f;

    float* H    = sH[w];
    float* lam_ = sLam[w];
    float* tmp_ = sTmp[w];
    float* dd_  = sD[w];
    float* uu   = sU[w];
    float* up   = sUp[w];
    float* dup  = sDup[w];

    for (int it = 0; it < kITERS; ++it) {
        // (A) stage u (plain + permuted) and lambda
        if (t < 40) { uu[t] = u_r; up[pp] = u_r; }
        lam_[t] = l0; lam_[64 + t] = l1; if (t < 20) lam_[128 + t] = l2;
        __syncthreads();

        // (C) rp = G u + s - h   (slots: j = t, t+64, t+128)
        float g0, g1, g2 = 0.f;
        if (t < 40) g0 = u_r; else g0 = rowdot40(&sBp[(t - 40) * BPST], up);
        g1 = rowdot40(&sBp[(t + 24) * BPST], up);
        if (t < 20) g2 = rowdot40(&sBp[(t + 88) * BPST], up);
        const float rp0 = g0 + s0 - h0, rp1 = g1 + s1 - h1, rp2 = g2 + s2 - h2;

        // (D) mu
        float part = s0 * l0 + s1 * l1 + ((t < 20) ? s2 * l2 : 0.f);
        const float mu = waveSum(part) * (1.f / 148.f);

        // (E) rc, d, tmp=(rc+lam*rp)/s
        const float rc0 = kSIGMA * mu - s0 * l0;
        const float rc1 = kSIGMA * mu - s1 * l1;
        const float rc2 = kSIGMA * mu - s2 * l2;
        const float d0 = l0 / s0, d1 = l1 / s1, d2 = l2 / s2;
        const float t0 = (rc0 + l0 * rp0) / s0;
        const float t1 = (rc1 + l1 * rp1) / s1;
        const float t2 = (rc2 + l2 * rp2) / s2;
        tmp_[t] = t0; tmp_[64 + t] = t1; if (t < 20) tmp_[128 + t] = t2;
        dd_[t]  = d0; dd_[64 + t]  = d1; if (t < 20) dd_[128 + t]  = d2;
        __syncthreads();

        // (B+F) fused rd and rhs: rhs = -(u@Q + p + lam@G + tmp@G)
        float rhs_r = 0.f;
        if (t < 40) {
            float accd = p_r + l0;   // lam identity part
            float acct = t0;         // tmp identity part
#pragma unroll 4
            for (int j = 0; j < 40; ++j) accd = fmaf(uu[j], Qg[j * 40 + t], accd);
#pragma unroll 4
            for (int j = 0; j < kNB; ++j) {
                const float bc = sBp[j * BPST + pp];
                accd = fmaf(lam_[40 + j], bc, accd);
                acct = fmaf(tmp_[40 + j], bc, acct);
            }
            rhs_r = -(accd + acct);
        }

        // (G) H = Q + diag(d[:40]) + B^T diag(d[40:]) B   (sparsity grouped)
        float A_[5][5];
#pragma unroll
        for (int a = 0; a < 5; ++a)
#pragma unroll
            for (int c = 0; c < 5; ++c)
                A_[a][c] = Qg[(li + 8 * a) * 40 + (lk + 8 * c)];
        if (li == lk) {
#pragma unroll
            for (int a = 0; a < 5; ++a) A_[a][a] += dd_[li + 8 * a];
        }
#pragma unroll
        for (int g = 0; g < 5; ++g) {
            const int na = g + 1;
            const int lo = 24 * g;
            const int hi = (g < 4) ? 24 * (g + 1) : 108;
            for (int j = lo; j < hi; ++j) {
                const float ddj = dd_[40 + j];
                const float* br = &sBp[j * BPST];
                float bi[5], bk[5];
#pragma unroll
                for (int a = 0; a < na; ++a) { bi[a] = br[li * 5 + a]; bk[a] = br[lk * 5 + a]; }
#pragma unroll
                for (int a = 0; a < na; ++a) {
                    const float f = ddj * bi[a];
#pragma unroll
                    for (int c = 0; c < na; ++c) A_[a][c] = fmaf(f, bk[c], A_[a][c]);
                }
            }
        }
#pragma unroll
        for (int a = 0; a < 5; ++a)
#pragma unroll
            for (int c = 0; c < 5; ++c)
                H[(li + 8 * a) * 41 + (lk + 8 * c)] = A_[a][c];
        __syncthreads();

        // (H) in-place Cholesky (lower); diagonal stores reciprocal of L[k][k]
        for (int k = 0; k < 40; ++k) {
            const float hkk = H[k * 41 + k];
            const float rk = 1.0f / sqrtf(hkk);
            const bool act = (t > k) && (t < 40);
            float lik = 0.f;
            if (act) { lik = H[t * 41 + k] * rk; H[t * 41 + k] = lik; }
            if (t == k) H[k * 41 + k] = rk;
            for (int j = k + 1; j < 40; ++j) {
                const float ljk = H[j * 41 + k];
                if (act && j <= t) H[t * 41 + j] -= lik * ljk;
            }
        }

        // (I) forward/backward triangular solves; y in registers (lane t holds y[t])
        float yv = (t < 40) ? rhs_r : 0.f;
        for (int k = 0; k < 40; ++k) {
            const float rk = H[k * 41 + k];
            if (t == k) yv *= rk;
            const float yk = __shfl(yv, k, 64);
            if (t > k && t < 40) yv = fmaf(-H[t * 41 + k], yk, yv);
        }
        for (int k = 39; k >= 0; --k) {
            const float rk = H[k * 41 + k];
            if (t == k) yv *= rk;
            const float xk = __shfl(yv, k, 64);
            if (t < k) yv = fmaf(-H[k * 41 + t], xk, yv);
        }
        const float du_r = yv;   // valid for t<40

        // (J) Gdu, ds, dlam, step length, updates
        if (t < 40) dup[pp] = du_r;
        __syncthreads();
        float q0, q1, q2 = 0.f;
        if (t < 40) q0 = du_r; else q0 = rowdot40(&sBp[(t - 40) * BPST], dup);
        q1 = rowdot40(&sBp[(t + 24) * BPST], dup);
        if (t < 20) q2 = rowdot40(&sBp[(t + 88) * BPST], dup);

        const float ds0 = -rp0 - q0, ds1 = -rp1 - q1, ds2 = -rp2 - q2;
        const float dl0 = (rc0 + l0 * (rp0 + q0)) / s0;
        const float dl1 = (rc1 + l1 * (rp1 + q1)) / s1;
        const float dl2 = (rc2 + l2 * (rp2 + q2)) / s2;

        float am = kBIG;
        am = fminf(am, (ds0 < 0.f) ? (-s0 / ds0) : kBIG);
        am = fminf(am, (dl0 < 0.f) ? (-l0 / dl0) : kBIG);
        am = fminf(am, (ds1 < 0.f) ? (-s1 / ds1) : kBIG);
        am = fminf(am, (dl1 < 0.f) ? (-l1 / dl1) : kBIG);
        if (t < 20) {
            am = fminf(am, (ds2 < 0.f) ? (-s2 / ds2) : kBIG);
            am = fminf(am, (dl2 < 0.f) ? (-l2 / dl2) : kBIG);
        }
        am = waveMin(am);
        const float alpha = fminf(1.f, 0.99f * am);

        if (t < 40) u_r = fmaf(alpha, du_r, u_r);
        s0 = fmaf(alpha, ds0, s0); l0 = fmaf(alpha, dl0, l0);
        s1 = fmaf(alpha, ds1, s1); l1 = fmaf(alpha, dl1, l1);
        if (t < 20) { s2 = fmaf(alpha, ds2, s2); l2 = fmaf(alpha, dl2, l2); }
        __syncthreads();
    }

    // epilogue: Q_value = sum_i u_i*(0.5*(uQ)_i + p_i) ; u0 = u[0]
    if (t < 40) uu[t] = u_r;
    __syncthreads();
    float qv = 0.f;
    if (t < 40) {
        float uq = 0.f;
        for (int j = 0; j < 40; ++j) uq = fmaf(uu[j], Qg[j * 40 + t], uq);
        qv = u_r * (0.5f * uq + p_r);
    }
    qv = waveSum(qv);
    if (t == 0) { out[e] = qv; out[kBATCH + e] = u_r; }
}

// ---------------------------------------------------------------------------
extern "C" void kernel_launch(void* const* d_in, const int* in_sizes, int n_in,
                              void* d_out, int out_size, void* d_ws, size_t ws_size,
                              hipStream_t stream) {
    const float* x  = (const float*)d_in[0];
    const float* W1 = (const float*)d_in[1];
    const float* b1 = (const float*)d_in[2];
    const float* W2 = (const float*)d_in[3];
    const float* b2 = (const float*)d_in[4];
    const float* L  = (const float*)d_in[5];
    const float* LP = (const float*)d_in[6];
    const float* LR = (const float*)d_in[7];
    const float* A  = (const float*)d_in[8];
    const float* Bm = (const float*)d_in[9];
    const float* u0 = (const float*)d_in[10];
    const float* s0 = (const float*)d_in[11];
    float* out = (float*)d_out;
    float* ws  = (float*)d_ws;

    float* Qg  = ws;           // 1600
    float* Bpg = ws + 1600;    // 108*44 = 4752
    float* hg  = ws + 6352;    // 148
    float* pg  = ws + 6512;    // 4096*40

    setup_kernel<<<1, 256, 0, stream>>>(L, LP, LR, A, Bm, u0, s0, Qg, Bpg, hg);
    mlp_kernel<<<kBATCH, 64, 0, stream>>>(x, W1, b1, W2, b2, pg);
    ipm_kernel<<<kBATCH / 4, 256, 0, stream>>>(Qg, Bpg, hg, pg, out);
}